// Round 1
// baseline (10856.746 us; speedup 1.0000x reference)
//
#include <hip/hip_runtime.h>

#define NN 50000
#define NE 800000

// ---------------- fp32 tiled GEMM: C[N,M] = A[N,K] @ B[K,M] ----------------
// 64x64 tile, BK=16, 256 threads, 4x4 microkernel. K,M multiples of 16/64.
__global__ __launch_bounds__(256) void gemm64(const float* __restrict__ A,
                                              const float* __restrict__ B,
                                              float* __restrict__ C,
                                              int N, int K, int M) {
    __shared__ float As[16][68];   // As[k][row], +4 pad keeps float4 rows 16B-aligned
    __shared__ float Bs[16][68];   // Bs[k][col]
    const int tid = threadIdx.x;
    const int tx = tid & 15;       // col group (4 cols)
    const int ty = tid >> 4;       // row group (4 rows)
    const int rowBase = blockIdx.y * 64;
    const int colBase = blockIdx.x * 64;

    float acc[4][4] = {};

    for (int k0 = 0; k0 < K; k0 += 16) {
        // Stage A tile: thread loads 4 elems, coalesced over k within a row
        {
            const int kk = tid & 15;
            const int r4 = tid >> 4;
#pragma unroll
            for (int i = 0; i < 4; ++i) {
                const int r = r4 * 4 + i;
                const int row = rowBase + r;
                float v = 0.f;
                if (row < N) v = A[(long long)row * K + (k0 + kk)];
                As[kk][r] = v;
            }
        }
        // Stage B tile: coalesced over cols
        {
            const int col = tid & 63;
            const int kg = tid >> 6;
#pragma unroll
            for (int i = 0; i < 4; ++i) {
                const int kk = kg * 4 + i;
                Bs[kk][col] = B[(long long)(k0 + kk) * M + (colBase + col)];
            }
        }
        __syncthreads();
#pragma unroll
        for (int kk = 0; kk < 16; ++kk) {
            const float4 av = *(const float4*)&As[kk][ty * 4];
            const float4 bv = *(const float4*)&Bs[kk][tx * 4];
            const float a[4] = {av.x, av.y, av.z, av.w};
            const float b[4] = {bv.x, bv.y, bv.z, bv.w};
#pragma unroll
            for (int i = 0; i < 4; ++i)
#pragma unroll
                for (int j = 0; j < 4; ++j)
                    acc[i][j] += a[i] * b[j];
        }
        __syncthreads();
    }

#pragma unroll
    for (int i = 0; i < 4; ++i) {
        const int row = rowBase + ty * 4 + i;
        if (row < N) {
            float4 v = make_float4(acc[i][0], acc[i][1], acc[i][2], acc[i][3]);
            *(float4*)&C[(long long)row * M + colBase + tx * 4] = v;
        }
    }
}

// ---------------- out[n*D + d] = b[d] (D power of two) ----------------
__global__ void bias_init(float* __restrict__ out, const float* __restrict__ b,
                          long long total, int dmask) {
    long long i = (long long)blockIdx.x * blockDim.x + threadIdx.x;
    const long long stride = (long long)gridDim.x * blockDim.x;
    for (; i < total; i += stride) out[i] = b[(int)(i & dmask)];
}

__global__ void relu_inplace(float* __restrict__ x, long long total) {
    long long i = (long long)blockIdx.x * blockDim.x + threadIdx.x;
    const long long stride = (long long)gridDim.x * blockDim.x;
    for (; i < total; i += stride) x[i] = fmaxf(x[i], 0.f);
}

// ---------------- scatter-add: out[dst[e]] += w[e] * h[src[e]] ----------------
// D = 4 << shift. One thread per (edge, float4 of dims).
__global__ void spmm_scatter(const int* __restrict__ src, const int* __restrict__ dst,
                             const float* __restrict__ w, const float* __restrict__ h,
                             float* __restrict__ out, int shift) {
    const long long total = (long long)NE << shift;   // E * (D/4)
    const int mask = (1 << shift) - 1;
    long long i = (long long)blockIdx.x * blockDim.x + threadIdx.x;
    const long long stride = (long long)gridDim.x * blockDim.x;
    for (; i < total; i += stride) {
        const int e  = (int)(i >> shift);
        const int d4 = (int)(i & mask);
        const int s  = src[e];
        const int d  = dst[e];
        const float ww = w[e];
        const float4 hv = *(const float4*)&h[((long long)s << (shift + 2)) + (d4 << 2)];
        float* o = &out[((long long)d << (shift + 2)) + (d4 << 2)];
        atomicAdd(o + 0, ww * hv.x);
        atomicAdd(o + 1, ww * hv.y);
        atomicAdd(o + 2, ww * hv.z);
        atomicAdd(o + 3, ww * hv.w);
    }
}

extern "C" void kernel_launch(void* const* d_in, const int* in_sizes, int n_in,
                              void* d_out, int out_size, void* d_ws, size_t ws_size,
                              hipStream_t stream) {
    const float* x    = (const float*)d_in[0];
    const int*   esrc = (const int*)d_in[1];
    const int*   edst = (const int*)d_in[2];
    const float* ew   = (const float*)d_in[3];
    const float* W1 = (const float*)d_in[4];  const float* b1 = (const float*)d_in[5];
    const float* W2 = (const float*)d_in[6];  const float* b2 = (const float*)d_in[7];
    const float* W3 = (const float*)d_in[8];  const float* b3 = (const float*)d_in[9];
    const float* W4 = (const float*)d_in[10]; const float* b4 = (const float*)d_in[11];
    float* out = (float*)d_out;

    float* bufA = (float*)d_ws;                       // N x 512 fp32 (102.4 MB)
    float* bufB = bufA + (long long)NN * 512;         // N x 512 fp32 (102.4 MB)

    auto gemm = [&](const float* A, const float* W, float* C, int K, int M) {
        dim3 grid(M / 64, (NN + 63) / 64);
        gemm64<<<grid, 256, 0, stream>>>(A, W, C, NN, K, M);
    };

    auto layer = [&](const float* hin, const float* W, const float* b,
                     int K, int M, float* tmp, float* hout, bool relu) {
        gemm(hin, W, tmp, K, M);                      // tmp = hin @ W
        const long long total = (long long)NN * M;
        int blocks = (int)((total + 255) / 256);
        bias_init<<<blocks, 256, 0, stream>>>(hout, b, total, M - 1);
        int shift = 0;
        { int v = M / 4; while ((1 << shift) < v) ++shift; }   // log2(M/4)
        long long etotal = (long long)NE << shift;
        long long eb = (etotal + 255) / 256;
        int eblocks = (int)(eb > 409600 ? 409600 : eb);
        spmm_scatter<<<eblocks, 256, 0, stream>>>(esrc, edst, ew, tmp, hout, shift);
        if (relu) relu_inplace<<<blocks, 256, 0, stream>>>(hout, total);
    };

    layer(x,    W1, b1, 512, 512, bufA, bufB, true);   // h1 in bufB (N x 512)
    layer(bufB, W2, b2, 512, 256, bufA, bufB, true);   // h2 in bufB (N x 256)
    layer(bufB, W3, b3, 256, 128, bufA, bufB, true);   // h3 in bufB (N x 128)
    layer(bufB, W4, b4, 128,  64, bufA, out,  false);  // emb -> d_out (N x 64)
}

// Round 2
// 1406.450 us; speedup vs baseline: 7.7193x; 7.7193x over previous
//
#include <hip/hip_runtime.h>

#define NN 50000
#define NE 800000

// ---------------- fp32 tiled GEMM: C[N,M] = A[N,K] @ B[K,M] ----------------
__global__ __launch_bounds__(256) void gemm64(const float* __restrict__ A,
                                              const float* __restrict__ B,
                                              float* __restrict__ C,
                                              int N, int K, int M) {
    __shared__ float As[16][68];
    __shared__ float Bs[16][68];
    const int tid = threadIdx.x;
    const int tx = tid & 15;
    const int ty = tid >> 4;
    const int rowBase = blockIdx.y * 64;
    const int colBase = blockIdx.x * 64;

    float acc[4][4] = {};

    for (int k0 = 0; k0 < K; k0 += 16) {
        {
            const int kk = tid & 15;
            const int r4 = tid >> 4;
#pragma unroll
            for (int i = 0; i < 4; ++i) {
                const int r = r4 * 4 + i;
                const int row = rowBase + r;
                float v = 0.f;
                if (row < N) v = A[(long long)row * K + (k0 + kk)];
                As[kk][r] = v;
            }
        }
        {
            const int col = tid & 63;
            const int kg = tid >> 6;
#pragma unroll
            for (int i = 0; i < 4; ++i) {
                const int kk = kg * 4 + i;
                Bs[kk][col] = B[(long long)(k0 + kk) * M + (colBase + col)];
            }
        }
        __syncthreads();
#pragma unroll
        for (int kk = 0; kk < 16; ++kk) {
            const float4 av = *(const float4*)&As[kk][ty * 4];
            const float4 bv = *(const float4*)&Bs[kk][tx * 4];
            const float a[4] = {av.x, av.y, av.z, av.w};
            const float b[4] = {bv.x, bv.y, bv.z, bv.w};
#pragma unroll
            for (int i = 0; i < 4; ++i)
#pragma unroll
                for (int j = 0; j < 4; ++j)
                    acc[i][j] += a[i] * b[j];
        }
        __syncthreads();
    }

#pragma unroll
    for (int i = 0; i < 4; ++i) {
        const int row = rowBase + ty * 4 + i;
        if (row < N) {
            float4 v = make_float4(acc[i][0], acc[i][1], acc[i][2], acc[i][3]);
            *(float4*)&C[(long long)row * M + colBase + tx * 4] = v;
        }
    }
}

// ---------------- CSR build ----------------
__global__ void zero_counts(int* __restrict__ counts) {
    int i = blockIdx.x * blockDim.x + threadIdx.x;
    if (i < NN) counts[i] = 0;
}

__global__ void hist_dst(const int* __restrict__ dst, int* __restrict__ counts) {
    int i = blockIdx.x * blockDim.x + threadIdx.x;
    const int stride = gridDim.x * blockDim.x;
    for (; i < NE; i += stride) atomicAdd(&counts[dst[i]], 1);
}

// Single-block two-level exclusive scan over NN counts.
// Writes offs[0..NN] (offs[NN]=E) and rewrites counts[] with the exclusive
// prefix (to serve as the fill cursor).
__global__ __launch_bounds__(1024) void scan_counts(int* __restrict__ counts,
                                                    int* __restrict__ offs) {
    __shared__ int sums[1024];
    const int tid = threadIdx.x;
    const int chunk = (NN + 1023) / 1024;   // 49
    const int beg = tid * chunk;
    const int end = min(beg + chunk, NN);
    int s = 0;
    for (int i = beg; i < end; ++i) s += counts[i];
    sums[tid] = s;
    __syncthreads();
    // block scan (inclusive) over sums
    for (int off = 1; off < 1024; off <<= 1) {
        int t = (tid >= off) ? sums[tid - off] : 0;
        __syncthreads();
        sums[tid] += t;
        __syncthreads();
    }
    int run = (tid == 0) ? 0 : sums[tid - 1];   // exclusive base for this chunk
    for (int i = beg; i < end; ++i) {
        const int v = counts[i];
        offs[i] = run;
        counts[i] = run;    // cursor
        run += v;
    }
    if (tid == 1023) offs[NN] = sums[1023];
}

__global__ void fill_csr(const int* __restrict__ src, const int* __restrict__ dst,
                         const float* __restrict__ w, int* __restrict__ cursor,
                         int* __restrict__ csr_src, float* __restrict__ csr_w) {
    int i = blockIdx.x * blockDim.x + threadIdx.x;
    const int stride = gridDim.x * blockDim.x;
    for (; i < NE; i += stride) {
        const int p = atomicAdd(&cursor[dst[i]], 1);
        csr_src[p] = src[i];
        csr_w[p] = w[i];
    }
}

// ---------------- gather SpMM: out[i] = relu?(bias + sum_j w_j * h[src_j]) ----
template <int D, int RELU>
__global__ __launch_bounds__(256) void spmm_gather(const int* __restrict__ offs,
                                                   const int* __restrict__ csr_src,
                                                   const float* __restrict__ csr_w,
                                                   const float* __restrict__ hp,
                                                   const float* __restrict__ bias,
                                                   float* __restrict__ out) {
    constexpr int TPN = D / 4;          // threads per node
    constexpr int NPB = 256 / TPN;      // nodes per block
    const int tid = threadIdx.x;
    const int node = blockIdx.x * NPB + tid / TPN;
    const int d = (tid % TPN) * 4;
    if (node >= NN) return;
    const int beg = offs[node];
    const int end = offs[node + 1];

    float4 acc = make_float4(0.f, 0.f, 0.f, 0.f);
    int j = beg;
    for (; j + 2 <= end; j += 2) {
        const int s0 = csr_src[j];
        const int s1 = csr_src[j + 1];
        const float w0 = csr_w[j];
        const float w1 = csr_w[j + 1];
        const float4 h0 = *(const float4*)&hp[(long long)s0 * D + d];
        const float4 h1 = *(const float4*)&hp[(long long)s1 * D + d];
        acc.x += w0 * h0.x + w1 * h1.x;
        acc.y += w0 * h0.y + w1 * h1.y;
        acc.z += w0 * h0.z + w1 * h1.z;
        acc.w += w0 * h0.w + w1 * h1.w;
    }
    if (j < end) {
        const int s0 = csr_src[j];
        const float w0 = csr_w[j];
        const float4 h0 = *(const float4*)&hp[(long long)s0 * D + d];
        acc.x += w0 * h0.x;
        acc.y += w0 * h0.y;
        acc.z += w0 * h0.z;
        acc.w += w0 * h0.w;
    }
    const float4 bv = *(const float4*)&bias[d];
    float4 r = make_float4(acc.x + bv.x, acc.y + bv.y, acc.z + bv.z, acc.w + bv.w);
    if (RELU) {
        r.x = fmaxf(r.x, 0.f);
        r.y = fmaxf(r.y, 0.f);
        r.z = fmaxf(r.z, 0.f);
        r.w = fmaxf(r.w, 0.f);
    }
    *(float4*)&out[(long long)node * D + d] = r;
}

extern "C" void kernel_launch(void* const* d_in, const int* in_sizes, int n_in,
                              void* d_out, int out_size, void* d_ws, size_t ws_size,
                              hipStream_t stream) {
    const float* x    = (const float*)d_in[0];
    const int*   esrc = (const int*)d_in[1];
    const int*   edst = (const int*)d_in[2];
    const float* ew   = (const float*)d_in[3];
    const float* W1 = (const float*)d_in[4];  const float* b1 = (const float*)d_in[5];
    const float* W2 = (const float*)d_in[6];  const float* b2 = (const float*)d_in[7];
    const float* W3 = (const float*)d_in[8];  const float* b3 = (const float*)d_in[9];
    const float* W4 = (const float*)d_in[10]; const float* b4 = (const float*)d_in[11];
    float* out = (float*)d_out;

    // workspace layout
    char* ws = (char*)d_ws;
    int*   offs    = (int*)ws;                    ws += (NN + 1) * sizeof(int);
    int*   counts  = (int*)ws;                    ws += NN * sizeof(int);   // then cursor
    int*   csr_src = (int*)ws;                    ws += NE * sizeof(int);
    float* csr_w   = (float*)ws;                  ws += NE * sizeof(float);
    ws = (char*)(((uintptr_t)ws + 255) & ~(uintptr_t)255);
    float* bufA = (float*)ws;                     // N x 512 fp32
    float* bufB = bufA + (long long)NN * 512;     // N x 512 fp32

    // ---- build CSR (per call; ws is re-poisoned each launch) ----
    zero_counts<<<(NN + 255) / 256, 256, 0, stream>>>(counts);
    hist_dst<<<3125, 256, 0, stream>>>(edst, counts);
    scan_counts<<<1, 1024, 0, stream>>>(counts, offs);
    fill_csr<<<3125, 256, 0, stream>>>(esrc, edst, ew, counts, csr_src, csr_w);

    auto gemm = [&](const float* A, const float* W, float* C, int K, int M) {
        dim3 grid(M / 64, (NN + 63) / 64);
        gemm64<<<grid, 256, 0, stream>>>(A, W, C, NN, K, M);
    };

    auto gather = [&](const float* tmp, const float* b, float* hout, int M, bool relu) {
        const int grid = NN / (256 / (M / 4));   // NN divisible by all NPB here
        if (M == 512) {
            if (relu) spmm_gather<512, 1><<<grid, 256, 0, stream>>>(offs, csr_src, csr_w, tmp, b, hout);
            else      spmm_gather<512, 0><<<grid, 256, 0, stream>>>(offs, csr_src, csr_w, tmp, b, hout);
        } else if (M == 256) {
            if (relu) spmm_gather<256, 1><<<grid, 256, 0, stream>>>(offs, csr_src, csr_w, tmp, b, hout);
            else      spmm_gather<256, 0><<<grid, 256, 0, stream>>>(offs, csr_src, csr_w, tmp, b, hout);
        } else if (M == 128) {
            if (relu) spmm_gather<128, 1><<<grid, 256, 0, stream>>>(offs, csr_src, csr_w, tmp, b, hout);
            else      spmm_gather<128, 0><<<grid, 256, 0, stream>>>(offs, csr_src, csr_w, tmp, b, hout);
        } else {
            if (relu) spmm_gather<64, 1><<<grid, 256, 0, stream>>>(offs, csr_src, csr_w, tmp, b, hout);
            else      spmm_gather<64, 0><<<grid, 256, 0, stream>>>(offs, csr_src, csr_w, tmp, b, hout);
        }
    };

    auto layer = [&](const float* hin, const float* W, const float* b,
                     int K, int M, float* tmp, float* hout, bool relu) {
        gemm(hin, W, tmp, K, M);          // tmp = hin @ W
        gather(tmp, b, hout, M, relu);    // hout = relu(adj @ tmp + b)
    };

    layer(x,    W1, b1, 512, 512, bufA, bufB, true);   // h1 in bufB
    layer(bufB, W2, b2, 512, 256, bufA, bufB, true);   // h2 in bufB
    layer(bufB, W3, b3, 256, 128, bufA, bufB, true);   // h3 in bufB
    layer(bufB, W4, b4, 128,  64, bufA, out,  false);  // emb -> d_out
}

// Round 3
// 903.641 us; speedup vs baseline: 12.0144x; 1.5564x over previous
//
#include <hip/hip_runtime.h>

#define NN 50000
#define NE 800000

typedef __attribute__((ext_vector_type(8))) short short8;
typedef __attribute__((ext_vector_type(4))) float float4v;

struct us4 { unsigned short x, y, z, w; };

__device__ __forceinline__ unsigned short f2bf(float f) {
    unsigned u = __float_as_uint(f);
    unsigned r = (u + 0x7FFF + ((u >> 16) & 1)) >> 16;   // RNE
    return (unsigned short)r;
}

__device__ __forceinline__ void gload_lds16(const unsigned short* g, unsigned short* l) {
    __builtin_amdgcn_global_load_lds(
        (const __attribute__((address_space(1))) unsigned int*)g,
        (__attribute__((address_space(3))) unsigned int*)l,
        16, 0, 0);
}

// ---------------- bf16 MFMA GEMM: C[N,M] = A[N,K] @ Bt[M,K]^T ----------------
// A row-major bf16 [N,K]; Bt row-major bf16 [M,K] (i.e. W transposed).
// 256 threads = 4 waves; BM x BN tile; each wave WM x WN; BK=32 (one MFMA K).
template <int BM, int BN, int WM, int WN>
__global__ __launch_bounds__(256) void gemm_mfma(const unsigned short* __restrict__ A,
                                                 const unsigned short* __restrict__ Bt,
                                                 float* __restrict__ C,
                                                 int N, int K, int M) {
    constexpr int BK = 32;
    constexpr int MT = WM / 16;
    constexpr int NT = WN / 16;
    constexpr int WCOLS = BN / WN;

    __shared__ __align__(16) unsigned short As[BM * BK];
    __shared__ __align__(16) unsigned short Bs[BN * BK];

    const int tid = threadIdx.x;
    const int lane = tid & 63;
    const int wid = tid >> 6;
    const int col16 = lane & 15;
    const int q = lane >> 4;             // 0..3
    const int wr = (wid / WCOLS) * WM;
    const int wc = (wid % WCOLS) * WN;
    const int rowBase = blockIdx.y * BM;
    const int colBase = blockIdx.x * BN;

    // staging lane geometry: lane covers row 16*l + lane/4, 16B chunk lane%4
    const int srow = lane >> 2;
    const int scol = (lane & 3) * 8;     // in bf16 elements

    float4v acc[MT][NT];
#pragma unroll
    for (int t = 0; t < MT; ++t)
#pragma unroll
        for (int u = 0; u < NT; ++u)
            acc[t][u] = (float4v)0.f;

    for (int k0 = 0; k0 < K; k0 += BK) {
        __syncthreads();   // protect LDS from overwrite while prior reads in flight
        // stage A: BM/16 wave-loads of 1024B
#pragma unroll
        for (int l = wid; l < BM / 16; l += 4) {
            int row = rowBase + 16 * l + srow;
            row = row < N ? row : N - 1;
            gload_lds16(A + (size_t)row * K + k0 + scol, &As[l * 512]);
        }
        // stage B
#pragma unroll
        for (int l = wid; l < BN / 16; l += 4) {
            const int row = colBase + 16 * l + srow;   // row of Bt = output col
            gload_lds16(Bt + (size_t)row * K + k0 + scol, &Bs[l * 512]);
        }
        __syncthreads();   // barrier drains vmcnt -> staging complete

        short8 a[MT], b[NT];
#pragma unroll
        for (int t = 0; t < MT; ++t)
            a[t] = *(const short8*)&As[(wr + t * 16 + col16) * BK + q * 8];
#pragma unroll
        for (int u = 0; u < NT; ++u)
            b[u] = *(const short8*)&Bs[(wc + u * 16 + col16) * BK + q * 8];
#pragma unroll
        for (int t = 0; t < MT; ++t)
#pragma unroll
            for (int u = 0; u < NT; ++u)
                acc[t][u] = __builtin_amdgcn_mfma_f32_16x16x32_bf16(a[t], b[u], acc[t][u], 0, 0, 0);
    }

    // epilogue: C/D layout col=lane&15, row=q*4+reg
#pragma unroll
    for (int t = 0; t < MT; ++t) {
        const int row0 = rowBase + wr + t * 16 + q * 4;
#pragma unroll
        for (int u = 0; u < NT; ++u) {
            const int col = colBase + wc + u * 16 + col16;
#pragma unroll
            for (int r = 0; r < 4; ++r) {
                const int row = row0 + r;
                if (row < N) C[(size_t)row * M + col] = acc[t][u][r];
            }
        }
    }
}

// ---------------- conversions ----------------
__global__ void cvt_f32_bf16(const float* __restrict__ in, unsigned short* __restrict__ out,
                             long long n4) {   // n4 = n/4
    long long i = (long long)blockIdx.x * blockDim.x + threadIdx.x;
    const long long stride = (long long)gridDim.x * blockDim.x;
    for (; i < n4; i += stride) {
        const float4 v = *(const float4*)&in[i * 4];
        us4 o = {f2bf(v.x), f2bf(v.y), f2bf(v.z), f2bf(v.w)};
        *(us4*)&out[i * 4] = o;
    }
}

__global__ void cvt_transpose(const float* __restrict__ W, unsigned short* __restrict__ Wt,
                              int K, int M) {
    int idx = blockIdx.x * blockDim.x + threadIdx.x;
    const int total = K * M;
    if (idx < total) {
        const int k = idx / M;
        const int m = idx % M;
        Wt[(size_t)m * K + k] = f2bf(W[idx]);
    }
}

// ---------------- CSR build ----------------
__global__ void zero_counts(int* __restrict__ counts) {
    int i = blockIdx.x * blockDim.x + threadIdx.x;
    if (i < NN) counts[i] = 0;
}

__global__ void hist_dst(const int* __restrict__ dst, int* __restrict__ counts) {
    int i = blockIdx.x * blockDim.x + threadIdx.x;
    const int stride = gridDim.x * blockDim.x;
    for (; i < NE; i += stride) atomicAdd(&counts[dst[i]], 1);
}

__global__ __launch_bounds__(1024) void scan_counts(int* __restrict__ counts,
                                                    int* __restrict__ offs) {
    __shared__ int sums[1024];
    const int tid = threadIdx.x;
    const int chunk = (NN + 1023) / 1024;
    const int beg = tid * chunk;
    const int end = min(beg + chunk, NN);
    int s = 0;
    for (int i = beg; i < end; ++i) s += counts[i];
    sums[tid] = s;
    __syncthreads();
    for (int off = 1; off < 1024; off <<= 1) {
        int t = (tid >= off) ? sums[tid - off] : 0;
        __syncthreads();
        sums[tid] += t;
        __syncthreads();
    }
    int run = (tid == 0) ? 0 : sums[tid - 1];
    for (int i = beg; i < end; ++i) {
        const int v = counts[i];
        offs[i] = run;
        counts[i] = run;
        run += v;
    }
    if (tid == 1023) offs[NN] = sums[1023];
}

__global__ void fill_csr(const int* __restrict__ src, const int* __restrict__ dst,
                         const float* __restrict__ w, int* __restrict__ cursor,
                         int* __restrict__ csr_src, float* __restrict__ csr_w) {
    int i = blockIdx.x * blockDim.x + threadIdx.x;
    const int stride = gridDim.x * blockDim.x;
    for (; i < NE; i += stride) {
        const int p = atomicAdd(&cursor[dst[i]], 1);
        csr_src[p] = src[i];
        csr_w[p] = w[i];
    }
}

// ---------------- gather SpMM ----------------
// OUTBF=1: write bf16 (ushort) h for the next GEMM; OUTBF=0: write fp32.
template <int D, int RELU, int OUTBF>
__global__ __launch_bounds__(256) void spmm_gather(const int* __restrict__ offs,
                                                   const int* __restrict__ csr_src,
                                                   const float* __restrict__ csr_w,
                                                   const float* __restrict__ hp,
                                                   const float* __restrict__ bias,
                                                   void* __restrict__ outv) {
    constexpr int TPN = D / 4;
    constexpr int NPB = 256 / TPN;
    const int tid = threadIdx.x;
    const int node = blockIdx.x * NPB + tid / TPN;
    const int d = (tid % TPN) * 4;
    if (node >= NN) return;
    const int beg = offs[node];
    const int end = offs[node + 1];

    float4 acc = make_float4(0.f, 0.f, 0.f, 0.f);
    int j = beg;
    for (; j + 2 <= end; j += 2) {
        const int s0 = csr_src[j];
        const int s1 = csr_src[j + 1];
        const float w0 = csr_w[j];
        const float w1 = csr_w[j + 1];
        const float4 h0 = *(const float4*)&hp[(long long)s0 * D + d];
        const float4 h1 = *(const float4*)&hp[(long long)s1 * D + d];
        acc.x += w0 * h0.x + w1 * h1.x;
        acc.y += w0 * h0.y + w1 * h1.y;
        acc.z += w0 * h0.z + w1 * h1.z;
        acc.w += w0 * h0.w + w1 * h1.w;
    }
    if (j < end) {
        const int s0 = csr_src[j];
        const float w0 = csr_w[j];
        const float4 h0 = *(const float4*)&hp[(long long)s0 * D + d];
        acc.x += w0 * h0.x;
        acc.y += w0 * h0.y;
        acc.z += w0 * h0.z;
        acc.w += w0 * h0.w;
    }
    const float4 bv = *(const float4*)&bias[d];
    float4 r = make_float4(acc.x + bv.x, acc.y + bv.y, acc.z + bv.z, acc.w + bv.w);
    if (RELU) {
        r.x = fmaxf(r.x, 0.f);
        r.y = fmaxf(r.y, 0.f);
        r.z = fmaxf(r.z, 0.f);
        r.w = fmaxf(r.w, 0.f);
    }
    if (OUTBF) {
        us4 o = {f2bf(r.x), f2bf(r.y), f2bf(r.z), f2bf(r.w)};
        *(us4*)((unsigned short*)outv + (long long)node * D + d) = o;
    } else {
        *(float4*)((float*)outv + (long long)node * D + d) = r;
    }
}

extern "C" void kernel_launch(void* const* d_in, const int* in_sizes, int n_in,
                              void* d_out, int out_size, void* d_ws, size_t ws_size,
                              hipStream_t stream) {
    const float* x    = (const float*)d_in[0];
    const int*   esrc = (const int*)d_in[1];
    const int*   edst = (const int*)d_in[2];
    const float* ew   = (const float*)d_in[3];
    const float* W1 = (const float*)d_in[4];  const float* b1 = (const float*)d_in[5];
    const float* W2 = (const float*)d_in[6];  const float* b2 = (const float*)d_in[7];
    const float* W3 = (const float*)d_in[8];  const float* b3 = (const float*)d_in[9];
    const float* W4 = (const float*)d_in[10]; const float* b4 = (const float*)d_in[11];
    float* out = (float*)d_out;

    // workspace layout (~161 MB; round-1 used ~212 MB so this fits)
    char* ws = (char*)d_ws;
    int*   offs    = (int*)ws;                    ws += (NN + 1) * sizeof(int);
    int*   counts  = (int*)ws;                    ws += NN * sizeof(int);
    int*   csr_src = (int*)ws;                    ws += NE * sizeof(int);
    float* csr_w   = (float*)ws;                  ws += NE * sizeof(float);
    unsigned short* Wt1 = (unsigned short*)ws;    ws += 512 * 512 * sizeof(unsigned short);
    unsigned short* Wt2 = (unsigned short*)ws;    ws += 256 * 512 * sizeof(unsigned short);
    unsigned short* Wt3 = (unsigned short*)ws;    ws += 128 * 256 * sizeof(unsigned short);
    unsigned short* Wt4 = (unsigned short*)ws;    ws += 64 * 128 * sizeof(unsigned short);
    ws = (char*)(((uintptr_t)ws + 255) & ~(uintptr_t)255);
    float* tmp = (float*)ws;                      ws += (size_t)NN * 512 * sizeof(float);
    unsigned short* hb = (unsigned short*)ws;     // N x 512 bf16; holds x, then h1..h3

    // ---- CSR build ----
    zero_counts<<<(NN + 255) / 256, 256, 0, stream>>>(counts);
    hist_dst<<<3125, 256, 0, stream>>>(edst, counts);
    scan_counts<<<1, 1024, 0, stream>>>(counts, offs);
    fill_csr<<<3125, 256, 0, stream>>>(esrc, edst, ew, counts, csr_src, csr_w);

    // ---- input / weight conversion ----
    cvt_f32_bf16<<<12800, 256, 0, stream>>>(x, hb, (long long)NN * 512 / 4);
    cvt_transpose<<<(512 * 512 + 255) / 256, 256, 0, stream>>>(W1, Wt1, 512, 512);
    cvt_transpose<<<(512 * 256 + 255) / 256, 256, 0, stream>>>(W2, Wt2, 512, 256);
    cvt_transpose<<<(256 * 128 + 255) / 256, 256, 0, stream>>>(W3, Wt3, 256, 128);
    cvt_transpose<<<(128 * 64 + 255) / 256, 256, 0, stream>>>(W4, Wt4, 128, 64);

    const int nby = (NN + 127) / 128;   // 391

    // ---- layer 1: K=512, M=512 ----
    gemm_mfma<128, 128, 64, 64><<<dim3(4, nby), 256, 0, stream>>>(hb, Wt1, tmp, NN, 512, 512);
    spmm_gather<512, 1, 1><<<NN / 2, 256, 0, stream>>>(offs, csr_src, csr_w, tmp, b1, hb);
    // ---- layer 2: K=512, M=256 ----
    gemm_mfma<128, 128, 64, 64><<<dim3(2, nby), 256, 0, stream>>>(hb, Wt2, tmp, NN, 512, 256);
    spmm_gather<256, 1, 1><<<NN / 4, 256, 0, stream>>>(offs, csr_src, csr_w, tmp, b2, hb);
    // ---- layer 3: K=256, M=128 ----
    gemm_mfma<128, 128, 64, 64><<<dim3(1, nby), 256, 0, stream>>>(hb, Wt3, tmp, NN, 256, 128);
    spmm_gather<128, 1, 1><<<NN / 8, 256, 0, stream>>>(offs, csr_src, csr_w, tmp, b3, hb);
    // ---- layer 4: K=128, M=64 ----
    gemm_mfma<128, 64, 32, 64><<<dim3(1, nby), 256, 0, stream>>>(hb, Wt4, tmp, NN, 128, 64);
    spmm_gather<64, 0, 0><<<NN / 16, 256, 0, stream>>>(offs, csr_src, csr_w, tmp, b4, out);
}

// Round 4
// 724.231 us; speedup vs baseline: 14.9907x; 1.2477x over previous
//
#include <hip/hip_runtime.h>

#define NN 50000
#define NE 800000

typedef __attribute__((ext_vector_type(8))) short short8;
typedef __attribute__((ext_vector_type(4))) float float4v;

struct us4 { unsigned short x, y, z, w; };
struct us8 { unsigned short v[8]; };

__device__ __forceinline__ unsigned short f2bf(float f) {
    unsigned u = __float_as_uint(f);
    unsigned r = (u + 0x7FFF + ((u >> 16) & 1)) >> 16;   // RNE
    return (unsigned short)r;
}

__device__ __forceinline__ float bf2f(unsigned short u) {
    return __uint_as_float((unsigned)u << 16);
}

__device__ __forceinline__ void gload_lds16(const unsigned short* g, unsigned short* l) {
    __builtin_amdgcn_global_load_lds(
        (const __attribute__((address_space(1))) unsigned int*)g,
        (__attribute__((address_space(3))) unsigned int*)l,
        16, 0, 0);
}

// ---------------- bf16 MFMA GEMM: C[N,M] = A[N,K] @ Bt[M,K]^T ----------------
// A row-major bf16 [N,K]; Bt row-major bf16 [M,K]. Output bf16 (OUTBF) or fp32.
template <int BM, int BN, int WM, int WN, int OUTBF>
__global__ __launch_bounds__(256) void gemm_mfma(const unsigned short* __restrict__ A,
                                                 const unsigned short* __restrict__ Bt,
                                                 void* __restrict__ Cv,
                                                 int N, int K, int M) {
    constexpr int BK = 32;
    constexpr int MT = WM / 16;
    constexpr int NT = WN / 16;
    constexpr int WCOLS = BN / WN;

    __shared__ __align__(16) unsigned short As[BM * BK];
    __shared__ __align__(16) unsigned short Bs[BN * BK];

    const int tid = threadIdx.x;
    const int lane = tid & 63;
    const int wid = tid >> 6;
    const int col16 = lane & 15;
    const int q = lane >> 4;
    const int wr = (wid / WCOLS) * WM;
    const int wc = (wid % WCOLS) * WN;
    const int rowBase = blockIdx.y * BM;
    const int colBase = blockIdx.x * BN;

    const int srow = lane >> 2;
    const int scol = (lane & 3) * 8;

    float4v acc[MT][NT];
#pragma unroll
    for (int t = 0; t < MT; ++t)
#pragma unroll
        for (int u = 0; u < NT; ++u)
            acc[t][u] = (float4v)0.f;

    for (int k0 = 0; k0 < K; k0 += BK) {
        __syncthreads();
#pragma unroll
        for (int l = wid; l < BM / 16; l += 4) {
            int row = rowBase + 16 * l + srow;
            row = row < N ? row : N - 1;
            gload_lds16(A + (size_t)row * K + k0 + scol, &As[l * 512]);
        }
#pragma unroll
        for (int l = wid; l < BN / 16; l += 4) {
            const int row = colBase + 16 * l + srow;
            gload_lds16(Bt + (size_t)row * K + k0 + scol, &Bs[l * 512]);
        }
        __syncthreads();

        short8 a[MT], b[NT];
#pragma unroll
        for (int t = 0; t < MT; ++t)
            a[t] = *(const short8*)&As[(wr + t * 16 + col16) * BK + q * 8];
#pragma unroll
        for (int u = 0; u < NT; ++u)
            b[u] = *(const short8*)&Bs[(wc + u * 16 + col16) * BK + q * 8];
#pragma unroll
        for (int t = 0; t < MT; ++t)
#pragma unroll
            for (int u = 0; u < NT; ++u)
                acc[t][u] = __builtin_amdgcn_mfma_f32_16x16x32_bf16(a[t], b[u], acc[t][u], 0, 0, 0);
    }

    // epilogue: C/D layout col=lane&15, row=q*4+reg
#pragma unroll
    for (int t = 0; t < MT; ++t) {
        const int row0 = rowBase + wr + t * 16 + q * 4;
#pragma unroll
        for (int u = 0; u < NT; ++u) {
            const int col = colBase + wc + u * 16 + col16;
#pragma unroll
            for (int r = 0; r < 4; ++r) {
                const int row = row0 + r;
                if (row < N) {
                    if (OUTBF)
                        ((unsigned short*)Cv)[(size_t)row * M + col] = f2bf(acc[t][u][r]);
                    else
                        ((float*)Cv)[(size_t)row * M + col] = acc[t][u][r];
                }
            }
        }
    }
}

// ---------------- conversions ----------------
__global__ void cvt_f32_bf16(const float* __restrict__ in, unsigned short* __restrict__ out,
                             long long n4) {
    long long i = (long long)blockIdx.x * blockDim.x + threadIdx.x;
    const long long stride = (long long)gridDim.x * blockDim.x;
    for (; i < n4; i += stride) {
        const float4 v = *(const float4*)&in[i * 4];
        us4 o = {f2bf(v.x), f2bf(v.y), f2bf(v.z), f2bf(v.w)};
        *(us4*)&out[i * 4] = o;
    }
}

__global__ void cvt_transpose(const float* __restrict__ W, unsigned short* __restrict__ Wt,
                              int K, int M) {
    int idx = blockIdx.x * blockDim.x + threadIdx.x;
    const int total = K * M;
    if (idx < total) {
        const int k = idx / M;
        const int m = idx % M;
        Wt[(size_t)m * K + k] = f2bf(W[idx]);
    }
}

// ---------------- CSR build ----------------
__global__ void zero_counts(int* __restrict__ counts) {
    int i = blockIdx.x * blockDim.x + threadIdx.x;
    if (i < NN) counts[i] = 0;
}

__global__ void hist_dst(const int* __restrict__ dst, int* __restrict__ counts) {
    int i = blockIdx.x * blockDim.x + threadIdx.x;
    const int stride = gridDim.x * blockDim.x;
    for (; i < NE; i += stride) atomicAdd(&counts[dst[i]], 1);
}

__global__ __launch_bounds__(1024) void scan_counts(int* __restrict__ counts,
                                                    int* __restrict__ offs) {
    __shared__ int sums[1024];
    const int tid = threadIdx.x;
    const int chunk = (NN + 1023) / 1024;
    const int beg = tid * chunk;
    const int end = min(beg + chunk, NN);
    int s = 0;
    for (int i = beg; i < end; ++i) s += counts[i];
    sums[tid] = s;
    __syncthreads();
    for (int off = 1; off < 1024; off <<= 1) {
        int t = (tid >= off) ? sums[tid - off] : 0;
        __syncthreads();
        sums[tid] += t;
        __syncthreads();
    }
    int run = (tid == 0) ? 0 : sums[tid - 1];
    for (int i = beg; i < end; ++i) {
        const int v = counts[i];
        offs[i] = run;
        counts[i] = run;
        run += v;
    }
    if (tid == 1023) offs[NN] = sums[1023];
}

__global__ void fill_csr(const int* __restrict__ src, const int* __restrict__ dst,
                         const float* __restrict__ w, int* __restrict__ cursor,
                         int* __restrict__ csr_src, float* __restrict__ csr_w) {
    int i = blockIdx.x * blockDim.x + threadIdx.x;
    const int stride = gridDim.x * blockDim.x;
    for (; i < NE; i += stride) {
        const int p = atomicAdd(&cursor[dst[i]], 1);
        csr_src[p] = src[i];
        csr_w[p] = w[i];
    }
}

// ---------------- gather SpMM (bf16 h input) ----------------
// out[i] = relu?(bias + sum_j w_j * h[src_j]); h is bf16 [NN, D].
// Each thread covers 8 dims (one 16B ushort8 load per edge).
template <int D, int RELU, int OUTBF>
__global__ __launch_bounds__(256) void spmm_gather(const int* __restrict__ offs,
                                                   const int* __restrict__ csr_src,
                                                   const float* __restrict__ csr_w,
                                                   const unsigned short* __restrict__ hp,
                                                   const float* __restrict__ bias,
                                                   void* __restrict__ outv) {
    constexpr int TPN = D / 8;          // threads per node
    constexpr int NPB = 256 / TPN;      // nodes per block
    const int tid = threadIdx.x;
    const int node = blockIdx.x * NPB + tid / TPN;
    const int d = (tid % TPN) * 8;
    if (node >= NN) return;
    const int beg = offs[node];
    const int end = offs[node + 1];

    float acc[8] = {};
    int j = beg;
    for (; j + 2 <= end; j += 2) {
        const int s0 = csr_src[j];
        const int s1 = csr_src[j + 1];
        const float w0 = csr_w[j];
        const float w1 = csr_w[j + 1];
        const us8 h0 = *(const us8*)&hp[(long long)s0 * D + d];
        const us8 h1 = *(const us8*)&hp[(long long)s1 * D + d];
#pragma unroll
        for (int k = 0; k < 8; ++k)
            acc[k] += w0 * bf2f(h0.v[k]) + w1 * bf2f(h1.v[k]);
    }
    if (j < end) {
        const int s0 = csr_src[j];
        const float w0 = csr_w[j];
        const us8 h0 = *(const us8*)&hp[(long long)s0 * D + d];
#pragma unroll
        for (int k = 0; k < 8; ++k)
            acc[k] += w0 * bf2f(h0.v[k]);
    }
#pragma unroll
    for (int k = 0; k < 8; ++k) {
        acc[k] += bias[d + k];
        if (RELU) acc[k] = fmaxf(acc[k], 0.f);
    }
    if (OUTBF) {
        us8 o;
#pragma unroll
        for (int k = 0; k < 8; ++k) o.v[k] = f2bf(acc[k]);
        *(us8*)((unsigned short*)outv + (long long)node * D + d) = o;
    } else {
        float* op = (float*)outv + (long long)node * D + d;
        *(float4*)op = make_float4(acc[0], acc[1], acc[2], acc[3]);
        *(float4*)(op + 4) = make_float4(acc[4], acc[5], acc[6], acc[7]);
    }
}

extern "C" void kernel_launch(void* const* d_in, const int* in_sizes, int n_in,
                              void* d_out, int out_size, void* d_ws, size_t ws_size,
                              hipStream_t stream) {
    const float* x    = (const float*)d_in[0];
    const int*   esrc = (const int*)d_in[1];
    const int*   edst = (const int*)d_in[2];
    const float* ew   = (const float*)d_in[3];
    const float* W1 = (const float*)d_in[4];  const float* b1 = (const float*)d_in[5];
    const float* W2 = (const float*)d_in[6];  const float* b2 = (const float*)d_in[7];
    const float* W3 = (const float*)d_in[8];  const float* b3 = (const float*)d_in[9];
    const float* W4 = (const float*)d_in[10]; const float* b4 = (const float*)d_in[11];
    float* out = (float*)d_out;

    // workspace layout (~115 MB)
    char* ws = (char*)d_ws;
    int*   offs    = (int*)ws;                    ws += (NN + 1) * sizeof(int);
    int*   counts  = (int*)ws;                    ws += NN * sizeof(int);
    int*   csr_src = (int*)ws;                    ws += NE * sizeof(int);
    float* csr_w   = (float*)ws;                  ws += NE * sizeof(float);
    unsigned short* Wt1 = (unsigned short*)ws;    ws += 512 * 512 * sizeof(unsigned short);
    unsigned short* Wt2 = (unsigned short*)ws;    ws += 256 * 512 * sizeof(unsigned short);
    unsigned short* Wt3 = (unsigned short*)ws;    ws += 128 * 256 * sizeof(unsigned short);
    unsigned short* Wt4 = (unsigned short*)ws;    ws += 64 * 128 * sizeof(unsigned short);
    ws = (char*)(((uintptr_t)ws + 255) & ~(uintptr_t)255);
    unsigned short* tmp = (unsigned short*)ws;    ws += (size_t)NN * 512 * sizeof(unsigned short);
    ws = (char*)(((uintptr_t)ws + 255) & ~(uintptr_t)255);
    unsigned short* hb = (unsigned short*)ws;     // N x 512 bf16; holds x, then h1..h3

    // ---- CSR build ----
    zero_counts<<<(NN + 255) / 256, 256, 0, stream>>>(counts);
    hist_dst<<<3125, 256, 0, stream>>>(edst, counts);
    scan_counts<<<1, 1024, 0, stream>>>(counts, offs);
    fill_csr<<<3125, 256, 0, stream>>>(esrc, edst, ew, counts, csr_src, csr_w);

    // ---- input / weight conversion ----
    cvt_f32_bf16<<<12800, 256, 0, stream>>>(x, hb, (long long)NN * 512 / 4);
    cvt_transpose<<<(512 * 512 + 255) / 256, 256, 0, stream>>>(W1, Wt1, 512, 512);
    cvt_transpose<<<(512 * 256 + 255) / 256, 256, 0, stream>>>(W2, Wt2, 512, 256);
    cvt_transpose<<<(256 * 128 + 255) / 256, 256, 0, stream>>>(W3, Wt3, 256, 128);
    cvt_transpose<<<(128 * 64 + 255) / 256, 256, 0, stream>>>(W4, Wt4, 128, 64);

    const int nby = (NN + 127) / 128;   // 391

    // ---- layer 1: K=512, M=512 ----
    gemm_mfma<128, 128, 64, 64, 1><<<dim3(4, nby), 256, 0, stream>>>(hb, Wt1, tmp, NN, 512, 512);
    spmm_gather<512, 1, 1><<<NN / 4, 256, 0, stream>>>(offs, csr_src, csr_w, tmp, b1, hb);
    // ---- layer 2: K=512, M=256 ----
    gemm_mfma<128, 128, 64, 64, 1><<<dim3(2, nby), 256, 0, stream>>>(hb, Wt2, tmp, NN, 512, 256);
    spmm_gather<256, 1, 1><<<NN / 8, 256, 0, stream>>>(offs, csr_src, csr_w, tmp, b2, hb);
    // ---- layer 3: K=256, M=128 ----
    gemm_mfma<128, 128, 64, 64, 1><<<dim3(1, nby), 256, 0, stream>>>(hb, Wt3, tmp, NN, 256, 128);
    spmm_gather<128, 1, 1><<<NN / 16, 256, 0, stream>>>(offs, csr_src, csr_w, tmp, b3, hb);
    // ---- layer 4: K=128, M=64 ----
    gemm_mfma<128, 64, 32, 64, 1><<<dim3(1, nby), 256, 0, stream>>>(hb, Wt4, tmp, NN, 128, 64);
    spmm_gather<64, 0, 0><<<(NN + 31) / 32, 256, 0, stream>>>(offs, csr_src, csr_w, tmp, b4, out);
}

// Round 5
// 622.466 us; speedup vs baseline: 17.4415x; 1.1635x over previous
//
#include <hip/hip_runtime.h>

#define NN 50000
#define NE 800000
#define SCAN_BLOCKS 196   // 196*256 = 50176 >= NN

typedef __attribute__((ext_vector_type(8))) short short8;
typedef __attribute__((ext_vector_type(4))) float float4v;

struct us4 { unsigned short x, y, z, w; };
struct us8 { unsigned short v[8]; };

__device__ __forceinline__ unsigned short f2bf(float f) {
    unsigned u = __float_as_uint(f);
    unsigned r = (u + 0x7FFF + ((u >> 16) & 1)) >> 16;   // RNE
    return (unsigned short)r;
}

__device__ __forceinline__ float bf2f(unsigned short u) {
    return __uint_as_float((unsigned)u << 16);
}

__device__ __forceinline__ void gload_lds16(const unsigned short* g, unsigned short* l) {
    __builtin_amdgcn_global_load_lds(
        (const __attribute__((address_space(1))) unsigned int*)g,
        (__attribute__((address_space(3))) unsigned int*)l,
        16, 0, 0);
}

// ---------------- bf16 MFMA GEMM: C[N,M] = A[N,K] @ Bt[M,K]^T ----------------
template <int BM, int BN, int WM, int WN, int OUTBF>
__global__ __launch_bounds__(256) void gemm_mfma(const unsigned short* __restrict__ A,
                                                 const unsigned short* __restrict__ Bt,
                                                 void* __restrict__ Cv,
                                                 int N, int K, int M) {
    constexpr int BK = 32;
    constexpr int MT = WM / 16;
    constexpr int NT = WN / 16;
    constexpr int WCOLS = BN / WN;

    __shared__ __align__(16) unsigned short As[BM * BK];
    __shared__ __align__(16) unsigned short Bs[BN * BK];

    const int tid = threadIdx.x;
    const int lane = tid & 63;
    const int wid = tid >> 6;
    const int col16 = lane & 15;
    const int q = lane >> 4;
    const int wr = (wid / WCOLS) * WM;
    const int wc = (wid % WCOLS) * WN;
    const int rowBase = blockIdx.y * BM;
    const int colBase = blockIdx.x * BN;

    const int srow = lane >> 2;
    const int scol = (lane & 3) * 8;

    float4v acc[MT][NT];
#pragma unroll
    for (int t = 0; t < MT; ++t)
#pragma unroll
        for (int u = 0; u < NT; ++u)
            acc[t][u] = (float4v)0.f;

    for (int k0 = 0; k0 < K; k0 += BK) {
        __syncthreads();
#pragma unroll
        for (int l = wid; l < BM / 16; l += 4) {
            int row = rowBase + 16 * l + srow;
            row = row < N ? row : N - 1;
            gload_lds16(A + (size_t)row * K + k0 + scol, &As[l * 512]);
        }
#pragma unroll
        for (int l = wid; l < BN / 16; l += 4) {
            const int row = colBase + 16 * l + srow;
            gload_lds16(Bt + (size_t)row * K + k0 + scol, &Bs[l * 512]);
        }
        __syncthreads();

        short8 a[MT], b[NT];
#pragma unroll
        for (int t = 0; t < MT; ++t)
            a[t] = *(const short8*)&As[(wr + t * 16 + col16) * BK + q * 8];
#pragma unroll
        for (int u = 0; u < NT; ++u)
            b[u] = *(const short8*)&Bs[(wc + u * 16 + col16) * BK + q * 8];
#pragma unroll
        for (int t = 0; t < MT; ++t)
#pragma unroll
            for (int u = 0; u < NT; ++u)
                acc[t][u] = __builtin_amdgcn_mfma_f32_16x16x32_bf16(a[t], b[u], acc[t][u], 0, 0, 0);
    }

    // epilogue: C/D layout col=lane&15, row=q*4+reg
#pragma unroll
    for (int t = 0; t < MT; ++t) {
        const int row0 = rowBase + wr + t * 16 + q * 4;
#pragma unroll
        for (int u = 0; u < NT; ++u) {
            const int col = colBase + wc + u * 16 + col16;
#pragma unroll
            for (int r = 0; r < 4; ++r) {
                const int row = row0 + r;
                if (row < N) {
                    if (OUTBF)
                        ((unsigned short*)Cv)[(size_t)row * M + col] = f2bf(acc[t][u][r]);
                    else
                        ((float*)Cv)[(size_t)row * M + col] = acc[t][u][r];
                }
            }
        }
    }
}

// ---------------- conversions ----------------
__global__ void cvt_f32_bf16(const float* __restrict__ in, unsigned short* __restrict__ out,
                             long long n4) {
    long long i = (long long)blockIdx.x * blockDim.x + threadIdx.x;
    const long long stride = (long long)gridDim.x * blockDim.x;
    for (; i < n4; i += stride) {
        const float4 v = *(const float4*)&in[i * 4];
        us4 o = {f2bf(v.x), f2bf(v.y), f2bf(v.z), f2bf(v.w)};
        *(us4*)&out[i * 4] = o;
    }
}

__global__ void cvt_transpose(const float* __restrict__ W, unsigned short* __restrict__ Wt,
                              int K, int M) {
    int idx = blockIdx.x * blockDim.x + threadIdx.x;
    const int total = K * M;
    if (idx < total) {
        const int k = idx / M;
        const int m = idx % M;
        Wt[(size_t)m * K + k] = f2bf(W[idx]);
    }
}

// ---------------- CSR build ----------------
__global__ void zero_counts(int* __restrict__ counts) {
    int i = blockIdx.x * blockDim.x + threadIdx.x;
    if (i < NN) counts[i] = 0;
}

__global__ void hist_dst(const int* __restrict__ dst, int* __restrict__ counts) {
    int i = blockIdx.x * blockDim.x + threadIdx.x;
    const int stride = gridDim.x * blockDim.x;
    for (; i < NE; i += stride) atomicAdd(&counts[dst[i]], 1);
}

// multi-block exclusive scan over counts[NN] -> offs[NN+1], cursor (=counts)
__global__ __launch_bounds__(256) void scan_partial(const int* __restrict__ counts,
                                                    int* __restrict__ partials) {
    __shared__ int r[256];
    const int t = threadIdx.x;
    const int i = blockIdx.x * 256 + t;
    r[t] = (i < NN) ? counts[i] : 0;
    __syncthreads();
    for (int s = 128; s > 0; s >>= 1) {
        if (t < s) r[t] += r[t + s];
        __syncthreads();
    }
    if (t == 0) partials[blockIdx.x] = r[0];
}

__global__ __launch_bounds__(256) void scan_base(const int* __restrict__ partials,
                                                 int* __restrict__ bases,
                                                 int* __restrict__ offs) {
    __shared__ int s[256];
    const int t = threadIdx.x;
    const int v = (t < SCAN_BLOCKS) ? partials[t] : 0;
    s[t] = v;
    __syncthreads();
    for (int off = 1; off < 256; off <<= 1) {
        int x = (t >= off) ? s[t - off] : 0;
        __syncthreads();
        s[t] += x;
        __syncthreads();
    }
    if (t < SCAN_BLOCKS) bases[t] = s[t] - v;   // exclusive base
    if (t == 255) offs[NN] = s[255];            // total = NE
}

__global__ __launch_bounds__(256) void scan_final(int* __restrict__ counts,
                                                  const int* __restrict__ bases,
                                                  int* __restrict__ offs) {
    __shared__ int s[256];
    const int t = threadIdx.x;
    const int i = blockIdx.x * 256 + t;
    const int v = (i < NN) ? counts[i] : 0;
    s[t] = v;
    __syncthreads();
    for (int off = 1; off < 256; off <<= 1) {
        int x = (t >= off) ? s[t - off] : 0;
        __syncthreads();
        s[t] += x;
        __syncthreads();
    }
    if (i < NN) {
        const int e = bases[blockIdx.x] + s[t] - v;   // exclusive prefix
        offs[i] = e;
        counts[i] = e;                                 // fill cursor
    }
}

__global__ void fill_csr(const int* __restrict__ src, const int* __restrict__ dst,
                         const float* __restrict__ w, int* __restrict__ cursor,
                         int* __restrict__ csr_src, float* __restrict__ csr_w) {
    int i = blockIdx.x * blockDim.x + threadIdx.x;
    const int stride = gridDim.x * blockDim.x;
    for (; i < NE; i += stride) {
        const int p = atomicAdd(&cursor[dst[i]], 1);
        csr_src[p] = src[i];
        csr_w[p] = w[i];
    }
}

// ---------------- gather SpMM (bf16 h input) ----------------
template <int D, int RELU, int OUTBF>
__global__ __launch_bounds__(256) void spmm_gather(const int* __restrict__ offs,
                                                   const int* __restrict__ csr_src,
                                                   const float* __restrict__ csr_w,
                                                   const unsigned short* __restrict__ hp,
                                                   const float* __restrict__ bias,
                                                   void* __restrict__ outv) {
    constexpr int TPN = D / 8;
    constexpr int NPB = 256 / TPN;
    const int tid = threadIdx.x;
    const int node = blockIdx.x * NPB + tid / TPN;
    const int d = (tid % TPN) * 8;
    if (node >= NN) return;
    const int beg = offs[node];
    const int end = offs[node + 1];

    float acc[8] = {};
    int j = beg;
    for (; j + 2 <= end; j += 2) {
        const int s0 = csr_src[j];
        const int s1 = csr_src[j + 1];
        const float w0 = csr_w[j];
        const float w1 = csr_w[j + 1];
        const us8 h0 = *(const us8*)&hp[(long long)s0 * D + d];
        const us8 h1 = *(const us8*)&hp[(long long)s1 * D + d];
#pragma unroll
        for (int k = 0; k < 8; ++k)
            acc[k] += w0 * bf2f(h0.v[k]) + w1 * bf2f(h1.v[k]);
    }
    if (j < end) {
        const int s0 = csr_src[j];
        const float w0 = csr_w[j];
        const us8 h0 = *(const us8*)&hp[(long long)s0 * D + d];
#pragma unroll
        for (int k = 0; k < 8; ++k)
            acc[k] += w0 * bf2f(h0.v[k]);
    }
#pragma unroll
    for (int k = 0; k < 8; ++k) {
        acc[k] += bias[d + k];
        if (RELU) acc[k] = fmaxf(acc[k], 0.f);
    }
    if (OUTBF) {
        us8 o;
#pragma unroll
        for (int k = 0; k < 8; ++k) o.v[k] = f2bf(acc[k]);
        *(us8*)((unsigned short*)outv + (long long)node * D + d) = o;
    } else {
        float* op = (float*)outv + (long long)node * D + d;
        *(float4*)op = make_float4(acc[0], acc[1], acc[2], acc[3]);
        *(float4*)(op + 4) = make_float4(acc[4], acc[5], acc[6], acc[7]);
    }
}

extern "C" void kernel_launch(void* const* d_in, const int* in_sizes, int n_in,
                              void* d_out, int out_size, void* d_ws, size_t ws_size,
                              hipStream_t stream) {
    const float* x    = (const float*)d_in[0];
    const int*   esrc = (const int*)d_in[1];
    const int*   edst = (const int*)d_in[2];
    const float* ew   = (const float*)d_in[3];
    const float* W1 = (const float*)d_in[4];  const float* b1 = (const float*)d_in[5];
    const float* W2 = (const float*)d_in[6];  const float* b2 = (const float*)d_in[7];
    const float* W3 = (const float*)d_in[8];  const float* b3 = (const float*)d_in[9];
    const float* W4 = (const float*)d_in[10]; const float* b4 = (const float*)d_in[11];
    float* out = (float*)d_out;

    // workspace layout (~115 MB)
    char* ws = (char*)d_ws;
    int*   offs    = (int*)ws;                    ws += (NN + 1) * sizeof(int);
    int*   counts  = (int*)ws;                    ws += NN * sizeof(int);
    int*   partials= (int*)ws;                    ws += 256 * sizeof(int);
    int*   bases   = (int*)ws;                    ws += 256 * sizeof(int);
    int*   csr_src = (int*)ws;                    ws += NE * sizeof(int);
    float* csr_w   = (float*)ws;                  ws += NE * sizeof(float);
    unsigned short* Wt1 = (unsigned short*)ws;    ws += 512 * 512 * sizeof(unsigned short);
    unsigned short* Wt2 = (unsigned short*)ws;    ws += 256 * 512 * sizeof(unsigned short);
    unsigned short* Wt3 = (unsigned short*)ws;    ws += 128 * 256 * sizeof(unsigned short);
    unsigned short* Wt4 = (unsigned short*)ws;    ws += 64 * 128 * sizeof(unsigned short);
    ws = (char*)(((uintptr_t)ws + 255) & ~(uintptr_t)255);
    unsigned short* tmp = (unsigned short*)ws;    ws += (size_t)NN * 512 * sizeof(unsigned short);
    ws = (char*)(((uintptr_t)ws + 255) & ~(uintptr_t)255);
    unsigned short* hb = (unsigned short*)ws;     // N x 512 bf16; holds x, then h1..h3

    // ---- CSR build ----
    zero_counts<<<(NN + 255) / 256, 256, 0, stream>>>(counts);
    hist_dst<<<3125, 256, 0, stream>>>(edst, counts);
    scan_partial<<<SCAN_BLOCKS, 256, 0, stream>>>(counts, partials);
    scan_base<<<1, 256, 0, stream>>>(partials, bases, offs);
    scan_final<<<SCAN_BLOCKS, 256, 0, stream>>>(counts, bases, offs);
    fill_csr<<<3125, 256, 0, stream>>>(esrc, edst, ew, counts, csr_src, csr_w);

    // ---- input / weight conversion ----
    cvt_f32_bf16<<<12800, 256, 0, stream>>>(x, hb, (long long)NN * 512 / 4);
    cvt_transpose<<<(512 * 512 + 255) / 256, 256, 0, stream>>>(W1, Wt1, 512, 512);
    cvt_transpose<<<(512 * 256 + 255) / 256, 256, 0, stream>>>(W2, Wt2, 512, 256);
    cvt_transpose<<<(256 * 128 + 255) / 256, 256, 0, stream>>>(W3, Wt3, 256, 128);
    cvt_transpose<<<(128 * 64 + 255) / 256, 256, 0, stream>>>(W4, Wt4, 128, 64);

    const int nby = (NN + 127) / 128;   // 391

    // ---- layer 1: K=512, M=512 ----
    gemm_mfma<128, 128, 64, 64, 1><<<dim3(4, nby), 256, 0, stream>>>(hb, Wt1, tmp, NN, 512, 512);
    spmm_gather<512, 1, 1><<<NN / 4, 256, 0, stream>>>(offs, csr_src, csr_w, tmp, b1, hb);
    // ---- layer 2: K=512, M=256 ----
    gemm_mfma<128, 128, 64, 64, 1><<<dim3(2, nby), 256, 0, stream>>>(hb, Wt2, tmp, NN, 512, 256);
    spmm_gather<256, 1, 1><<<NN / 8, 256, 0, stream>>>(offs, csr_src, csr_w, tmp, b2, hb);
    // ---- layer 3: K=256, M=128 ----
    gemm_mfma<128, 128, 64, 64, 1><<<dim3(1, nby), 256, 0, stream>>>(hb, Wt3, tmp, NN, 256, 128);
    spmm_gather<128, 1, 1><<<NN / 16, 256, 0, stream>>>(offs, csr_src, csr_w, tmp, b3, hb);
    // ---- layer 4: K=128, M=64 ----
    gemm_mfma<128, 64, 32, 64, 1><<<dim3(1, nby), 256, 0, stream>>>(hb, Wt4, tmp, NN, 128, 64);
    spmm_gather<64, 0, 0><<<(NN + 31) / 32, 256, 0, stream>>>(offs, csr_src, csr_w, tmp, b4, out);
}